// Round 1
// baseline (35.236 us; speedup 1.0000x reference)
//
#include <hip/hip_runtime.h>
#include <hip/hip_bf16.h>
#include <math.h>

// Smagorinsky SGS stress: tau = -2*CS^2*FW^2 * |S| * S
// velocity: [B=2, 3, N, N, N] f32 (axes: b, comp, z, y, x), periodic grid,
// dx = 2*pi/N, central differences.
// output:   [B=2, 6, N, N, N] f32, channels [S00,S11,S22,S01,S02,S12] scaled.

constexpr int N  = 128;
constexpr int N3 = N * N * N;          // 2^21
constexpr int B  = 2;

__global__ __launch_bounds__(256) void smag_kernel(const float* __restrict__ v,
                                                   float* __restrict__ out) {
    int idx = blockIdx.x * blockDim.x + threadIdx.x;   // over B*N3
    // exact grid, no bounds check needed (B*N3 % 256 == 0) — but keep it safe:
    if (idx >= B * N3) return;

    const int b = idx >> 21;           // N3 == 2^21
    const int s = idx & (N3 - 1);
    const int x = s & (N - 1);
    const int y = (s >> 7) & (N - 1);
    const int z = s >> 14;

    const int xp = (x + 1) & (N - 1), xm = (x - 1) & (N - 1);
    const int yp = (y + 1) & (N - 1), ym = (y - 1) & (N - 1);
    const int zp = (z + 1) & (N - 1), zm = (z - 1) & (N - 1);

    const int zy = (z << 14) | (y << 7);
    const int o_xp = zy | xp;
    const int o_xm = zy | xm;
    const int o_yp = (z << 14) | (yp << 7) | x;
    const int o_ym = (z << 14) | (ym << 7) | x;
    const int o_zp = (zp << 14) | (y << 7) | x;
    const int o_zm = (zm << 14) | (y << 7) | x;

    // dx = 2*pi/N  ->  1/(2*dx) = N/(4*pi)
    const float inv2dx = (float)(N / (4.0 * M_PI));

    const float* __restrict__ vb = v + (size_t)b * 3 * N3;

    float du[3][3];   // du[i][j] = d u_i / d x_j  (j: 0=z-axis(2),1=y,2=x)
#pragma unroll
    for (int c = 0; c < 3; ++c) {
        const float* __restrict__ vc = vb + (size_t)c * N3;
        du[c][0] = (vc[o_zp] - vc[o_zm]) * inv2dx;
        du[c][1] = (vc[o_yp] - vc[o_ym]) * inv2dx;
        du[c][2] = (vc[o_xp] - vc[o_xm]) * inv2dx;
    }

    const float S0 = du[0][0];
    const float S1 = du[1][1];
    const float S2 = du[2][2];
    const float S3 = 0.5f * (du[0][1] + du[1][0]);
    const float S4 = 0.5f * (du[0][2] + du[2][0]);
    const float S5 = 0.5f * (du[1][2] + du[2][1]);

    const float sum = S0 * S0 + S1 * S1 + S2 * S2 + S3 * S3 + S4 * S4 + S5 * S5;
    const float mag = sqrtf(2.0f * sum);

    // -2 * CS^2 * FILTER_WIDTH^2, CS = 0.18, FW = 1.0
    const float coef = -2.0f * 0.18f * 0.18f * mag;

    float* __restrict__ ob = out + (size_t)b * 6 * N3 + s;
    ob[0 * N3] = coef * S0;
    ob[1 * N3] = coef * S1;
    ob[2 * N3] = coef * S2;
    ob[3 * N3] = coef * S3;
    ob[4 * N3] = coef * S4;
    ob[5 * N3] = coef * S5;
}

extern "C" void kernel_launch(void* const* d_in, const int* in_sizes, int n_in,
                              void* d_out, int out_size, void* d_ws, size_t ws_size,
                              hipStream_t stream) {
    const float* v = (const float*)d_in[0];
    float* out = (float*)d_out;
    const int total = B * N3;                 // 4,194,304 threads
    const int block = 256;
    const int grid = total / block;           // 16384 blocks
    smag_kernel<<<grid, block, 0, stream>>>(v, out);
}

// Round 2
// 32.370 us; speedup vs baseline: 1.0885x; 1.0885x over previous
//
#include <hip/hip_runtime.h>
#include <hip/hip_bf16.h>
#include <math.h>

// Smagorinsky SGS stress: tau = -2*CS^2*FW^2 * |S| * S
// velocity: [B=2, 3, N, N, N] f32 (axes: b, comp, z, y, x), periodic grid.
// output:   [B=2, 6, N, N, N] f32, channels [S00,S11,S22,S01,S02,S12] scaled.
// Vectorized: each thread computes 4 consecutive x-cells with float4 traffic.

constexpr int N  = 128;
constexpr int N3 = N * N * N;          // 2^21
constexpr int B  = 2;

__global__ __launch_bounds__(256) void smag_kernel4(const float* __restrict__ v,
                                                    float* __restrict__ out) {
    const int idx = blockIdx.x * blockDim.x + threadIdx.x;   // over B*N3/4
    const int b = idx >> 19;                 // N3/4 == 2^19
    const int s = (idx & ((1 << 19) - 1)) << 2;   // base cell within batch
    const int x0 = s & (N - 1);
    const int y  = (s >> 7) & (N - 1);
    const int z  = s >> 14;

    const int yp = (y + 1) & (N - 1), ym = (y - 1) & (N - 1);
    const int zp = (z + 1) & (N - 1), zm = (z - 1) & (N - 1);
    const int xm  = (x0 - 1) & (N - 1);      // left edge (wraps at x0==0)
    const int xp4 = (x0 + 4) & (N - 1);      // right edge (wraps at x0==124)

    const int o_c  = (z << 14) | (y << 7) | x0;
    const int o_yp = (z << 14) | (yp << 7) | x0;
    const int o_ym = (z << 14) | (ym << 7) | x0;
    const int o_zp = (zp << 14) | (y << 7) | x0;
    const int o_zm = (zm << 14) | (y << 7) | x0;
    const int o_xm  = (z << 14) | (y << 7) | xm;
    const int o_xp4 = (z << 14) | (y << 7) | xp4;

    const float inv2dx = (float)(N / (4.0 * M_PI));   // 1/(2*dx), dx = 2*pi/N

    const float* __restrict__ vb = v + (size_t)b * 3 * N3;

    // du[c][j][k]: d u_c / d x_j at cell k (j: 0=z, 1=y, 2=x)
    float du[3][3][4];
#pragma unroll
    for (int c = 0; c < 3; ++c) {
        const float* __restrict__ vc = vb + (size_t)c * N3;
        const float4 cz_p = *reinterpret_cast<const float4*>(vc + o_zp);
        const float4 cz_m = *reinterpret_cast<const float4*>(vc + o_zm);
        const float4 cy_p = *reinterpret_cast<const float4*>(vc + o_yp);
        const float4 cy_m = *reinterpret_cast<const float4*>(vc + o_ym);
        const float4 cc   = *reinterpret_cast<const float4*>(vc + o_c);
        const float  el   = vc[o_xm];
        const float  er   = vc[o_xp4];

        du[c][0][0] = (cz_p.x - cz_m.x) * inv2dx;
        du[c][0][1] = (cz_p.y - cz_m.y) * inv2dx;
        du[c][0][2] = (cz_p.z - cz_m.z) * inv2dx;
        du[c][0][3] = (cz_p.w - cz_m.w) * inv2dx;

        du[c][1][0] = (cy_p.x - cy_m.x) * inv2dx;
        du[c][1][1] = (cy_p.y - cy_m.y) * inv2dx;
        du[c][1][2] = (cy_p.z - cy_m.z) * inv2dx;
        du[c][1][3] = (cy_p.w - cy_m.w) * inv2dx;

        du[c][2][0] = (cc.y - el)   * inv2dx;
        du[c][2][1] = (cc.z - cc.x) * inv2dx;
        du[c][2][2] = (cc.w - cc.y) * inv2dx;
        du[c][2][3] = (er   - cc.z) * inv2dx;
    }

    float4 t[6];
#pragma unroll
    for (int k = 0; k < 4; ++k) {
        const float S0 = du[0][0][k];
        const float S1 = du[1][1][k];
        const float S2 = du[2][2][k];
        const float S3 = 0.5f * (du[0][1][k] + du[1][0][k]);
        const float S4 = 0.5f * (du[0][2][k] + du[2][0][k]);
        const float S5 = 0.5f * (du[1][2][k] + du[2][1][k]);

        const float sum = S0*S0 + S1*S1 + S2*S2 + S3*S3 + S4*S4 + S5*S5;
        const float coef = -2.0f * 0.18f * 0.18f * sqrtf(2.0f * sum);

        (&t[0].x)[k] = coef * S0;
        (&t[1].x)[k] = coef * S1;
        (&t[2].x)[k] = coef * S2;
        (&t[3].x)[k] = coef * S3;
        (&t[4].x)[k] = coef * S4;
        (&t[5].x)[k] = coef * S5;
    }

    float* __restrict__ ob = out + (size_t)b * 6 * N3 + s;
#pragma unroll
    for (int ch = 0; ch < 6; ++ch) {
        *reinterpret_cast<float4*>(ob + (size_t)ch * N3) = t[ch];
    }
}

extern "C" void kernel_launch(void* const* d_in, const int* in_sizes, int n_in,
                              void* d_out, int out_size, void* d_ws, size_t ws_size,
                              hipStream_t stream) {
    const float* v = (const float*)d_in[0];
    float* out = (float*)d_out;
    const int total = B * N3 / 4;             // 1,048,576 threads
    const int block = 256;
    const int grid = total / block;           // 4096 blocks
    smag_kernel4<<<grid, block, 0, stream>>>(v, out);
}

// Round 4
// 31.841 us; speedup vs baseline: 1.1066x; 1.0166x over previous
//
#include <hip/hip_runtime.h>
#include <hip/hip_bf16.h>
#include <math.h>

// Smagorinsky SGS stress: tau = -2*CS^2*FW^2 * |S| * S
// velocity: [B=2, 3, N, N, N] f32 (axes: b, comp, z, y, x), periodic grid.
// output:   [B=2, 6, N, N, N] f32, channels [S00,S11,S22,S01,S02,S12] scaled.
//
// R4: 4 cells/thread (native float4 vectors), S accumulated in-place (lower
// VGPR peak -> more waves/SIMD), non-temporal stores (output is write-only;
// keep L2/L3 for the reusable input rows), inv2dx^2 folded into the final
// coefficient.

constexpr int N  = 128;
constexpr int N3 = N * N * N;          // 2^21
constexpr int B  = 2;

typedef float f32x4 __attribute__((ext_vector_type(4)));

__global__ __launch_bounds__(256) void smag_kernel4(const float* __restrict__ v,
                                                    float* __restrict__ out) {
    const int idx = blockIdx.x * blockDim.x + threadIdx.x;   // over B*N3/4
    const int b = idx >> 19;                       // N3/4 == 2^19
    const int s = (idx & ((1 << 19) - 1)) << 2;    // base cell within batch
    const int x0 = s & (N - 1);
    const int y  = (s >> 7) & (N - 1);
    const int z  = s >> 14;

    const int yp = (y + 1) & (N - 1), ym = (y - 1) & (N - 1);
    const int zp = (z + 1) & (N - 1), zm = (z - 1) & (N - 1);
    const int xm  = (x0 - 1) & (N - 1);      // left edge (wraps at x0==0)
    const int xp4 = (x0 + 4) & (N - 1);      // right edge (wraps at x0==124)

    const int zy   = (z << 14) | (y << 7);
    const int o_c  = zy | x0;
    const int o_yp = (z << 14) | (yp << 7) | x0;
    const int o_ym = (z << 14) | (ym << 7) | x0;
    const int o_zp = (zp << 14) | (y << 7) | x0;
    const int o_zm = (zm << 14) | (y << 7) | x0;
    const int o_xm  = zy | xm;
    const int o_xp4 = zy | xp4;

    const float* __restrict__ vb = v + (size_t)b * 3 * N3;

    // Running strain channels [S00,S11,S22,S01,S02,S12] x 4 cells (raw diffs;
    // derivative scaling folded into coef at the end).
    f32x4 S[6];

#pragma unroll
    for (int c = 0; c < 3; ++c) {
        const float* __restrict__ vc = vb + (size_t)c * N3;
        const f32x4 cz_p = *reinterpret_cast<const f32x4*>(vc + o_zp);
        const f32x4 cz_m = *reinterpret_cast<const f32x4*>(vc + o_zm);
        const f32x4 cy_p = *reinterpret_cast<const f32x4*>(vc + o_yp);
        const f32x4 cy_m = *reinterpret_cast<const f32x4*>(vc + o_ym);
        const f32x4 cc   = *reinterpret_cast<const f32x4*>(vc + o_c);
        const float  el  = vc[o_xm];
        const float  er  = vc[o_xp4];

        const f32x4 dz = cz_p - cz_m;                    // d/dz (axis 2)
        const f32x4 dy = cy_p - cy_m;                    // d/dy (axis 3)
        const f32x4 dxv = {cc.y - el, cc.z - cc.x,
                           cc.w - cc.y, er - cc.z};      // d/dx (axis 4)

        // du[i][j], j: 0=z-axis, 1=y, 2=x. Channels:
        // S0=du[0][0], S1=du[1][1], S2=du[2][2],
        // S3=0.5(du[0][1]+du[1][0]), S4=0.5(du[0][2]+du[2][0]),
        // S5=0.5(du[1][2]+du[2][1])
        if (c == 0) {
            S[0] = dz;
            S[3] = 0.5f * dy;
            S[4] = 0.5f * dxv;
        } else if (c == 1) {
            S[1] = dy;
            S[3] += 0.5f * dz;
            S[5] = 0.5f * dxv;
        } else {
            S[2] = dxv;
            S[4] += 0.5f * dz;
            S[5] += 0.5f * dy;
        }
    }

    // coef = -2*CS^2*FW^2 * inv2dx^2 * sqrt(2*sum(Sraw^2)),  inv2dx = N/(4*pi)
    const float inv2dx = (float)(N / (4.0 * M_PI));
    const float cmul = -2.0f * 0.18f * 0.18f * inv2dx * inv2dx;

    const f32x4 sum = S[0]*S[0] + S[1]*S[1] + S[2]*S[2]
                    + S[3]*S[3] + S[4]*S[4] + S[5]*S[5];
    f32x4 coef;
#pragma unroll
    for (int k = 0; k < 4; ++k) coef[k] = cmul * sqrtf(2.0f * sum[k]);

    float* __restrict__ ob = out + (size_t)b * 6 * N3 + s;
#pragma unroll
    for (int ch = 0; ch < 6; ++ch) {
        const f32x4 t = coef * S[ch];
        __builtin_nontemporal_store(t, reinterpret_cast<f32x4*>(ob + (size_t)ch * N3));
    }
}

extern "C" void kernel_launch(void* const* d_in, const int* in_sizes, int n_in,
                              void* d_out, int out_size, void* d_ws, size_t ws_size,
                              hipStream_t stream) {
    const float* v = (const float*)d_in[0];
    float* out = (float*)d_out;
    const int total = B * N3 / 4;             // 1,048,576 threads
    const int block = 256;
    const int grid = total / block;           // 4096 blocks
    smag_kernel4<<<grid, block, 0, stream>>>(v, out);
}

// Round 5
// 27.259 us; speedup vs baseline: 1.2926x; 1.1681x over previous
//
#include <hip/hip_runtime.h>
#include <hip/hip_bf16.h>
#include <math.h>

// Smagorinsky SGS stress: tau = -2*CS^2*FW^2 * |S| * S
// velocity: [B=2, 3, N, N, N] f32 (axes: b, comp, z, y, x), periodic grid.
// output:   [B=2, 6, N, N, N] f32, channels [S00,S11,S22,S01,S02,S12] scaled.
//
// R5: x-edge values via wave shuffle instead of scalar gathers (15 VMEM
// loads/thread instead of 21), chunked XCD-aware block swizzle so blocks
// sharing y/z halo rows land on the same XCD's L2. NT stores kept.

constexpr int N  = 128;
constexpr int N3 = N * N * N;          // 2^21
constexpr int B  = 2;
constexpr int NXCD = 8;

typedef float f32x4 __attribute__((ext_vector_type(4)));

__global__ __launch_bounds__(256) void smag_kernel4(const float* __restrict__ v,
                                                    float* __restrict__ out) {
    // Chunked XCD swizzle: default assignment is round-robin (bid % 8 -> XCD).
    // Remap so each XCD gets one contiguous chunk of the grid: blocks sharing
    // y-halos (bid +/-1) and z-halos (bid +/-16) then hit the same L2.
    const int nwg = gridDim.x;                 // 4096, divisible by 8
    const int chunk = nwg / NXCD;              // 512
    const int bid = (blockIdx.x % NXCD) * chunk + blockIdx.x / NXCD;

    const int idx = bid * blockDim.x + threadIdx.x;   // over B*N3/4
    const int b = idx >> 19;                       // N3/4 == 2^19
    const int s = (idx & ((1 << 19) - 1)) << 2;    // base cell within batch
    const int x0 = s & (N - 1);
    const int y  = (s >> 7) & (N - 1);
    const int z  = s >> 14;

    const int yp = (y + 1) & (N - 1), ym = (y - 1) & (N - 1);
    const int zp = (z + 1) & (N - 1), zm = (z - 1) & (N - 1);

    const int o_c  = (z << 14) | (y << 7) | x0;
    const int o_yp = (z << 14) | (yp << 7) | x0;
    const int o_ym = (z << 14) | (ym << 7) | x0;
    const int o_zp = (zp << 14) | (y << 7) | x0;
    const int o_zm = (zm << 14) | (y << 7) | x0;

    // One row of 128 floats = 32 lanes (4 cells each). Within a wave, lanes
    // 0-31 cover one row, lanes 32-63 the next (wave base is 2-row aligned).
    // x-edge neighbors live in adjacent lanes' center registers.
    const int lane = threadIdx.x & 63;
    const int src_el = (lane & 32) | ((lane - 1) & 31);  // previous lane in row
    const int src_er = (lane & 32) | ((lane + 1) & 31);  // next lane in row

    const float* __restrict__ vb = v + (size_t)b * 3 * N3;

    // Running strain channels [S00,S11,S22,S01,S02,S12] x 4 cells (raw diffs;
    // derivative scaling folded into coef at the end).
    f32x4 S[6];

#pragma unroll
    for (int c = 0; c < 3; ++c) {
        const float* __restrict__ vc = vb + (size_t)c * N3;
        const f32x4 cz_p = *reinterpret_cast<const f32x4*>(vc + o_zp);
        const f32x4 cz_m = *reinterpret_cast<const f32x4*>(vc + o_zm);
        const f32x4 cy_p = *reinterpret_cast<const f32x4*>(vc + o_yp);
        const f32x4 cy_m = *reinterpret_cast<const f32x4*>(vc + o_ym);
        const f32x4 cc   = *reinterpret_cast<const f32x4*>(vc + o_c);
        const float  el  = __shfl(cc.w, src_el, 64);   // left neighbor (wraps in-row)
        const float  er  = __shfl(cc.x, src_er, 64);   // right neighbor

        const f32x4 dz = cz_p - cz_m;                    // d/dz (axis 2)
        const f32x4 dy = cy_p - cy_m;                    // d/dy (axis 3)
        const f32x4 dxv = {cc.y - el, cc.z - cc.x,
                           cc.w - cc.y, er - cc.z};      // d/dx (axis 4)

        // du[i][j], j: 0=z-axis, 1=y, 2=x. Channels:
        // S0=du[0][0], S1=du[1][1], S2=du[2][2],
        // S3=0.5(du[0][1]+du[1][0]), S4=0.5(du[0][2]+du[2][0]),
        // S5=0.5(du[1][2]+du[2][1])
        if (c == 0) {
            S[0] = dz;
            S[3] = 0.5f * dy;
            S[4] = 0.5f * dxv;
        } else if (c == 1) {
            S[1] = dy;
            S[3] += 0.5f * dz;
            S[5] = 0.5f * dxv;
        } else {
            S[2] = dxv;
            S[4] += 0.5f * dz;
            S[5] += 0.5f * dy;
        }
    }

    // coef = -2*CS^2*FW^2 * inv2dx^2 * sqrt(2*sum(Sraw^2)),  inv2dx = N/(4*pi)
    const float inv2dx = (float)(N / (4.0 * M_PI));
    const float cmul = -2.0f * 0.18f * 0.18f * inv2dx * inv2dx;

    const f32x4 sum = S[0]*S[0] + S[1]*S[1] + S[2]*S[2]
                    + S[3]*S[3] + S[4]*S[4] + S[5]*S[5];
    f32x4 coef;
#pragma unroll
    for (int k = 0; k < 4; ++k) coef[k] = cmul * sqrtf(2.0f * sum[k]);

    float* __restrict__ ob = out + (size_t)b * 6 * N3 + s;
#pragma unroll
    for (int ch = 0; ch < 6; ++ch) {
        const f32x4 t = coef * S[ch];
        __builtin_nontemporal_store(t, reinterpret_cast<f32x4*>(ob + (size_t)ch * N3));
    }
}

extern "C" void kernel_launch(void* const* d_in, const int* in_sizes, int n_in,
                              void* d_out, int out_size, void* d_ws, size_t ws_size,
                              hipStream_t stream) {
    const float* v = (const float*)d_in[0];
    float* out = (float*)d_out;
    const int total = B * N3 / 4;             // 1,048,576 threads
    const int block = 256;
    const int grid = total / block;           // 4096 blocks
    smag_kernel4<<<grid, block, 0, stream>>>(v, out);
}